// Round 1
// baseline (372.669 us; speedup 1.0000x reference)
//
#include <hip/hip_runtime.h>
#include <climits>
#include <cstdint>

#define L 1000        // NUM_LABELS
#define NROWS 32768   // 64*512

// ws layout (int32 units):
//   [0,    1000)          first_row[label]  (INT_MAX if unseen)
//   [1024, 2024)          perm_final[pos]
//   [2048, 2048+32768)    evt_slot[row] = (lab<<10)|m  at first-occurrence rows, else -1

__global__ void k_init(int* __restrict__ first_row, int* __restrict__ evt_slot) {
    int i = blockIdx.x * blockDim.x + threadIdx.x;
    if (i < NROWS) evt_slot[i] = -1;
    if (i < L) first_row[i] = INT_MAX;
}

__global__ void k_first(const int* __restrict__ labels, int* __restrict__ first_row) {
    int i = blockIdx.x * blockDim.x + threadIdx.x;
    if (i < NROWS) atomicMin(&first_row[labels[i]], i);
}

// One block per label: argmax of the first-occurrence row, first-index tiebreak.
__global__ void k_argmax(const float* __restrict__ flat, const int* __restrict__ first_row,
                         int* __restrict__ evt_slot) {
    int lab = blockIdx.x;
    int row = first_row[lab];
    if (row == INT_MAX) return;
    const float* y = flat + (size_t)row * L;
    int tid = threadIdx.x;
    float bv = -INFINITY;
    int bk = 0x7fffffff;
    for (int k = tid; k < L; k += 256) {
        float v = y[k];
        if (v > bv) { bv = v; bk = k; }   // ascending k => strict > keeps first
    }
    __shared__ float sv[256];
    __shared__ int   sk[256];
    sv[tid] = bv; sk[tid] = bk;
    __syncthreads();
    for (int off = 128; off > 0; off >>= 1) {
        if (tid < off) {
            float v2 = sv[tid + off]; int k2 = sk[tid + off];
            if (v2 > sv[tid] || (v2 == sv[tid] && k2 < sk[tid])) { sv[tid] = v2; sk[tid] = k2; }
        }
        __syncthreads();
    }
    if (tid == 0) evt_slot[row] = (lab << 10) | sk[0];
}

// Single block: compact events in row order, replay transpositions, emit perm.
__global__ void __launch_bounds__(1024) k_seq(const int* __restrict__ evt_slot,
                                              int* __restrict__ perm_g) {
    __shared__ int evt[L];
    __shared__ int pos[L];
    __shared__ int scnt[1024];
    int tid = threadIdx.x;
    int base = tid * 32;                 // 1024 threads * 32 rows = 32768
    int c = 0;
    for (int j = 0; j < 32; j++) c += (evt_slot[base + j] >= 0) ? 1 : 0;
    scnt[tid] = c;
    __syncthreads();
    // Hillis-Steele inclusive scan (double-barrier per step)
    for (int off = 1; off < 1024; off <<= 1) {
        int v = scnt[tid];
        int add = (tid >= off) ? scnt[tid - off] : 0;
        __syncthreads();
        scnt[tid] = v + add;
        __syncthreads();
    }
    int K = scnt[1023];
    int w = tid ? scnt[tid - 1] : 0;
    for (int j = 0; j < 32; j++) {
        int v = evt_slot[base + j];
        if (v >= 0) evt[w++] = v;        // chunks contiguous => row order preserved
    }
    if (tid < L) pos[tid] = tid;         // pos = perm^{-1}, initially identity
    __syncthreads();
    if (tid == 0) {
        for (int i = 0; i < K; i++) {
            int v = evt[i];
            int lab = v >> 10;
            int m = v & 1023;
            int r = pos[m];              // argmax position in permuted space
            if (r != lab) {              // swap values r<->lab in perm
                int pr = pos[r];
                int pl = pos[lab];
                pos[r] = pl;
                pos[lab] = pr;
            }
        }
    }
    __syncthreads();
    if (tid < L) perm_g[pos[tid]] = tid; // invert: perm[pos[v]] = v
}

// 8 rows per block; LDS-staged row so global read AND write are coalesced float4.
#define RPB 8
__global__ void k_gather(const float* __restrict__ flat, const int* __restrict__ perm_g,
                         float* __restrict__ out) {
    __shared__ __align__(16) int   p[L];
    __shared__ __align__(16) float buf[L];
    int tid = threadIdx.x;
    for (int j = tid; j < L; j += 256) p[j] = perm_g[j];
    int row0 = blockIdx.x * RPB;
    for (int rr = 0; rr < RPB; rr++) {
        size_t off = (size_t)(row0 + rr) * L;
        __syncthreads();                              // buf reuse guard (+p ready on iter 0)
        if (tid < 250) ((float4*)buf)[tid] = ((const float4*)(flat + off))[tid];
        __syncthreads();
        if (tid < 250) {
            int j = tid * 4;
            float4 o;
            o.x = buf[p[j + 0]];
            o.y = buf[p[j + 1]];
            o.z = buf[p[j + 2]];
            o.w = buf[p[j + 3]];
            ((float4*)(out + off))[tid] = o;
        }
    }
}

extern "C" void kernel_launch(void* const* d_in, const int* in_sizes, int n_in,
                              void* d_out, int out_size, void* d_ws, size_t ws_size,
                              hipStream_t stream) {
    const float* flat   = (const float*)d_in[0];   // (64,512,1000) fp32
    const int*   labels = (const int*)d_in[1];     // (64,512) int32
    float* out = (float*)d_out;
    int* ws = (int*)d_ws;
    int* first_row = ws;          // 1000
    int* perm_g    = ws + 1024;   // 1000
    int* evt_slot  = ws + 2048;   // 32768

    k_init  <<<(NROWS + 255) / 256, 256, 0, stream>>>(first_row, evt_slot);
    k_first <<<(NROWS + 255) / 256, 256, 0, stream>>>(labels, first_row);
    k_argmax<<<L, 256, 0, stream>>>(flat, first_row, evt_slot);
    k_seq   <<<1, 1024, 0, stream>>>(evt_slot, perm_g);
    k_gather<<<NROWS / RPB, 256, 0, stream>>>(flat, perm_g, out);
}

// Round 2
// 351.146 us; speedup vs baseline: 1.0613x; 1.0613x over previous
//
#include <hip/hip_runtime.h>
#include <climits>
#include <cstdint>

#define L 1000        // NUM_LABELS
#define NROWS 32768   // 64*512

// ws layout (int32 units):
//   [0,    1000)          first_row[label]  (INT_MAX if unseen)
//   [1024, 2024)          perm_final[pos]
//   [2048, 2048+32768)    evt_slot[row] = (lab<<10)|m  at first-occurrence rows, else -1

__global__ void k_init(int* __restrict__ first_row, int* __restrict__ evt_slot) {
    int i = blockIdx.x * blockDim.x + threadIdx.x;
    if (i < NROWS) evt_slot[i] = -1;
    if (i < L) first_row[i] = INT_MAX;
}

__global__ void k_first(const int* __restrict__ labels, int* __restrict__ first_row) {
    int i = blockIdx.x * blockDim.x + threadIdx.x;
    if (i < NROWS) atomicMin(&first_row[labels[i]], i);
}

// One block per label: argmax of the first-occurrence row, first-index tiebreak.
__global__ void k_argmax(const float* __restrict__ flat, const int* __restrict__ first_row,
                         int* __restrict__ evt_slot) {
    int lab = blockIdx.x;
    int row = first_row[lab];
    if (row == INT_MAX) return;
    const float* y = flat + (size_t)row * L;
    int tid = threadIdx.x;
    float bv = -INFINITY;
    int bk = 0x7fffffff;
    for (int k = tid; k < L; k += 256) {
        float v = y[k];
        if (v > bv) { bv = v; bk = k; }   // ascending k => strict > keeps first
    }
    __shared__ float sv[256];
    __shared__ int   sk[256];
    sv[tid] = bv; sk[tid] = bk;
    __syncthreads();
    for (int off = 128; off > 0; off >>= 1) {
        if (tid < off) {
            float v2 = sv[tid + off]; int k2 = sk[tid + off];
            if (v2 > sv[tid] || (v2 == sv[tid] && k2 < sk[tid])) { sv[tid] = v2; sk[tid] = k2; }
        }
        __syncthreads();
    }
    if (tid == 0) evt_slot[row] = (lab << 10) | sk[0];
}

// Single block: compact events in row order, replay transpositions, emit perm.
// Replay is software-pipelined: next event's pos[m'], pos[lab'] are issued
// BEFORE this event's two writes (program order => they see pre-write values),
// then patched in registers against the written slots. One LDS round-trip/event.
__global__ void __launch_bounds__(1024) k_seq(const int* __restrict__ evt_slot,
                                              int* __restrict__ perm_g) {
    __shared__ int evt[1025];
    __shared__ int pos[L];
    __shared__ int scnt[1024];
    int tid = threadIdx.x;
    int base = tid * 32;                 // 1024 threads * 32 rows = 32768
    int c = 0;
    for (int j = 0; j < 32; j++) c += (evt_slot[base + j] >= 0) ? 1 : 0;
    scnt[tid] = c;
    __syncthreads();
    // Hillis-Steele inclusive scan
    for (int off = 1; off < 1024; off <<= 1) {
        int v = scnt[tid];
        int add = (tid >= off) ? scnt[tid - off] : 0;
        __syncthreads();
        scnt[tid] = v + add;
        __syncthreads();
    }
    int K = scnt[1023];
    int w = tid ? scnt[tid - 1] : 0;
    for (int j = 0; j < 32; j++) {
        int v = evt_slot[base + j];
        if (v >= 0) evt[w++] = v;        // chunks contiguous => row order preserved
    }
    if (tid < L) pos[tid] = tid;         // pos = perm^{-1}, initially identity
    __syncthreads();
    if (tid == 0 && K > 0) {
        evt[K] = evt[K - 1];             // sentinel for the 1-ahead prefetch
        int v0 = evt[0];
        int lab = v0 >> 10, m = v0 & 1023;
        int Pm = pos[m], Plab = pos[lab];
        for (int i = 0; i < K; i++) {
            int vn   = evt[i + 1];
            int labn = vn >> 10, mn = vn & 1023;
            int Pmn   = pos[mn];          // speculative (pre-write) reads
            int Plabn = pos[labn];
            int r = Pm;
            if (r != lab) {
                int pr = pos[r];          // the one dependent read
                pos[r]   = Plab;
                pos[lab] = pr;
                // patch speculative values against the two writes
                if (mn == r)        Pmn = Plab;
                else if (mn == lab) Pmn = pr;
                if (labn == r)        Plabn = Plab;
                else if (labn == lab) Plabn = pr;
            }
            Pm = Pmn; Plab = Plabn; lab = labn; m = mn;
        }
    }
    __syncthreads();
    if (tid < L) perm_g[pos[tid]] = tid; // invert: perm[pos[v]] = v
}

// 4 rows per block IN PARALLEL (four 256-thread groups sharing the p table).
// Global read and write fully coalesced float4; permuted gather goes via LDS.
__global__ void __launch_bounds__(1024) k_gather(const float* __restrict__ flat,
                                                 const int* __restrict__ perm_g,
                                                 float* __restrict__ out) {
    __shared__ __align__(16) int   p[1024];
    __shared__ __align__(16) float buf[4][L];
    int tid = threadIdx.x;
    if (tid < L) p[tid] = perm_g[tid];
    int g = tid >> 8;            // group 0..3 -> row within block
    int t = tid & 255;           // lane-in-group
    size_t row = (size_t)blockIdx.x * 4 + g;
    const float* src = flat + row * L;
    float*       dst = out  + row * L;
    float4 v;
    if (t < 250) v = ((const float4*)src)[t];
    __syncthreads();             // p visible; (v still in flight is fine)
    if (t < 250) ((float4*)buf[g])[t] = v;
    __syncthreads();             // buf visible
    if (t < 250) {
        int j = t * 4;
        float4 o;
        o.x = buf[g][p[j + 0]];
        o.y = buf[g][p[j + 1]];
        o.z = buf[g][p[j + 2]];
        o.w = buf[g][p[j + 3]];
        ((float4*)dst)[t] = o;
    }
}

extern "C" void kernel_launch(void* const* d_in, const int* in_sizes, int n_in,
                              void* d_out, int out_size, void* d_ws, size_t ws_size,
                              hipStream_t stream) {
    const float* flat   = (const float*)d_in[0];   // (64,512,1000) fp32
    const int*   labels = (const int*)d_in[1];     // (64,512) int32
    float* out = (float*)d_out;
    int* ws = (int*)d_ws;
    int* first_row = ws;          // 1000
    int* perm_g    = ws + 1024;   // 1000
    int* evt_slot  = ws + 2048;   // 32768

    k_init  <<<(NROWS + 255) / 256, 256, 0, stream>>>(first_row, evt_slot);
    k_first <<<(NROWS + 255) / 256, 256, 0, stream>>>(labels, first_row);
    k_argmax<<<L, 256, 0, stream>>>(flat, first_row, evt_slot);
    k_seq   <<<1, 1024, 0, stream>>>(evt_slot, perm_g);
    k_gather<<<NROWS / 4, 1024, 0, stream>>>(flat, perm_g, out);
}